// Round 11
// baseline (112.541 us; speedup 1.0000x reference)
//
#include <hip/hip_runtime.h>
#include <hip/hip_bf16.h>

typedef __bf16 bf16x8 __attribute__((ext_vector_type(8)));
typedef __bf16 bf16x4 __attribute__((ext_vector_type(4)));
typedef float  f32x4  __attribute__((ext_vector_type(4)));
typedef float  f4v    __attribute__((ext_vector_type(4)));

#define DEV __device__ __forceinline__

DEV void gload16(void* lds, const void* g) {
    __builtin_amdgcn_global_load_lds((const __attribute__((address_space(1))) void*)g,
                                     (__attribute__((address_space(3))) void*)lds, 16, 0, 0);
}

#define VMCNT(n) asm volatile("s_waitcnt vmcnt(" #n ")" ::: "memory")
#define LGKM0()  asm volatile("s_waitcnt lgkmcnt(0)" ::: "memory")
#define BAR()    __builtin_amdgcn_s_barrier()
#define BARM()   asm volatile("s_barrier" ::: "memory")
#define SCHEDB() __builtin_amdgcn_sched_barrier(0)

// ---------------- fused prepass: cvt(hid) | transpose(Wqkv) | transpose(Wproj) | cs tables ----------------
// grid = 5120 + 1200 + 400 + 160 = 6880 blocks of 256
__global__ __launch_bounds__(256) void k_prep(const float* __restrict__ hid, __bf16* __restrict__ hb,
                                              const float* __restrict__ Wqkv, __bf16* __restrict__ WqT,
                                              const float* __restrict__ Wproj, __bf16* __restrict__ WpT,
                                              const float* __restrict__ rcos, const float* __restrict__ rsin,
                                              __bf16* __restrict__ csb, __bf16* __restrict__ snb) {
    __shared__ float tile[64][65];
    const int b = blockIdx.x;
    const int tid = threadIdx.x;

    if (b < 5120) {
        int i = b * 256 + tid;
        f4v v = ((const f4v*)hid)[i];
        bf16x4 o;
        #pragma unroll
        for (int j = 0; j < 4; ++j) o[j] = (__bf16)v[j];
        ((bf16x4*)hb)[i] = o;
        return;
    }
    if (b < 5120 + 1200 + 400) {
        const float* in;
        __bf16* out;
        int R, C, bb, cb;
        if (b < 5120 + 1200) { in = Wqkv; out = WqT; R = 1280; C = 3840; cb = 60; bb = b - 5120; }
        else                 { in = Wproj; out = WpT; R = 1280; C = 1280; cb = 20; bb = b - 6320; }
        int br = (bb / cb) * 64, bc = (bb % cb) * 64;
        int tx = tid & 63, ty = tid >> 6;
        #pragma unroll
        for (int i = 0; i < 16; ++i) {
            int r = i * 4 + ty;
            tile[r][tx] = in[(size_t)(br + r) * C + (bc + tx)];
        }
        __syncthreads();
        #pragma unroll
        for (int i = 0; i < 16; ++i) {
            int r = i * 4 + ty;
            out[(size_t)(bc + r) * R + (br + tx)] = (__bf16)tile[tx][r];
        }
        return;
    }
    {
        int i = (b - 6720) * 256 + tid;
        f4v cv = ((const f4v*)rcos)[i];
        f4v sv = ((const f4v*)rsin)[i];
        bf16x4 co, so;
        #pragma unroll
        for (int j = 0; j < 4; ++j) { co[j] = (__bf16)cv[j]; so[j] = (__bf16)sv[j]; }
        ((bf16x4*)csb)[i] = co;
        ((bf16x4*)snb)[i] = so;
    }
}

// ---------------- 256x256 GEMM: 1 barrier + 1 vmcnt per K-tile, whole tile one sched region ----------------
// LDS per buffer (elems): A quarters [4][64][64] at 0 (q0=rows0-63,q1=128-191,q2=64-127,q3=192-255)
//                         B rows [256][64] at 16384
// Swizzle (elem space): col ^= (row&7)<<3  (both stage-source and ds_read)
// WAR safety: every ds_read of tile t-1 is consumed by an MFMA of tile t-1, so all
// reads of buf[(t-1)&1] are retired before any wave crosses BAR(t); stage(t+1) into
// that buffer after BAR(t) is safe. RAW: vmcnt(0) before BAR drains stage(t), which
// was issued one full tile (~2.5k cyc) earlier.
template<int MH>
DEV void read_a4(const __bf16* Abuf, int wm, int fr, int colsw, bf16x8 (&a)[4]) {
    const __bf16* p = Abuf + (MH * 2 + wm) * 4096 + fr * 64 + colsw;
    #pragma unroll
    for (int m = 0; m < 4; ++m)
        a[m] = *(const bf16x8*)__builtin_assume_aligned(p + m * 1024, 16);
}

DEV void read_b4(const __bf16* Bbuf, int wn, int fr, int colsw, bf16x8 (&b)[4]) {
    const __bf16* p = Bbuf + wn * 4096 + fr * 64 + colsw;
    #pragma unroll
    for (int n = 0; n < 4; ++n)
        b[n] = *(const bf16x8*)__builtin_assume_aligned(p + n * 1024, 16);
}

template<int MH>
DEV void mfma16(f32x4 (&acc)[8][4], const bf16x8 (&a)[4], const bf16x8 (&b)[4]) {
    __builtin_amdgcn_s_setprio(1);
    #pragma unroll
    for (int m = 0; m < 4; ++m)
        #pragma unroll
        for (int n = 0; n < 4; ++n)
            acc[MH * 4 + m][n] = __builtin_amdgcn_mfma_f32_16x16x32_bf16(a[m], b[n], acc[MH * 4 + m][n], 0, 0, 0);
    __builtin_amdgcn_s_setprio(0);
}

__global__ __launch_bounds__(512, 2) void k_gemm256(const __bf16* __restrict__ A,
                                                    const __bf16* __restrict__ B,
                                                    const float* __restrict__ bias,
                                                    __bf16* __restrict__ C,
                                                    __bf16* __restrict__ Vt,
                                                    int M, int N, int K) {
    __shared__ __align__(16) __bf16 lds[2][32768];
    const int tid = threadIdx.x;
    const int lane = tid & 63, w = tid >> 6;
    const int wm = w >> 2, wn = w & 3;
    const int g = lane >> 4, fr = lane & 15;

    const int nbn = N >> 8;
    const int nwg = gridDim.x;
    int bid = blockIdx.x;
    {   // bijective XCD swizzle
        int q = nwg >> 3, r = nwg & 7;
        int xcd = bid & 7, o = bid >> 3;
        bid = (xcd < r ? xcd * (q + 1) : r * (q + 1) + (xcd - r) * q) + o;
    }
    const int bm = bid / nbn, bn = bid % nbn;
    const int brow = bm << 8, bcol = bn << 8;

    const int si = tid >> 3;
    const int sc = ((tid & 7) ^ (si & 7)) << 3;
    const __bf16* Ab0 = A + (size_t)(brow + si) * K + sc;
    const __bf16* Bb0 = B + (size_t)(bcol + si) * K + sc;
    __bf16* l0 = &lds[0][0] + tid * 8;
    __bf16* l1 = &lds[1][0] + tid * 8;
    const size_t K64 = (size_t)64 * K, K128 = (size_t)128 * K, K192 = (size_t)192 * K;

    #define SA0(Lb, kt) { gload16((Lb),         Ab0 + (kt));        gload16((Lb) + 4096,  Ab0 + K128 + (kt)); }
    #define SA1(Lb, kt) { gload16((Lb) + 8192,  Ab0 + K64 + (kt));  gload16((Lb) + 12288, Ab0 + K192 + (kt)); }
    #define SB0(Lb, kt) { gload16((Lb) + 16384, Bb0 + (kt));        gload16((Lb) + 20480, Bb0 + K64 + (kt)); }
    #define SB1(Lb, kt) { gload16((Lb) + 24576, Bb0 + K128 + (kt)); gload16((Lb) + 28672, Bb0 + K192 + (kt)); }

    const int NT = K >> 6;
    f32x4 acc[8][4] = {};
    const int c0 = (g * 8) ^ ((fr & 7) << 3);
    const int c1 = c0 ^ 32;

    // prologue: stage tile0 -> buf0
    SA0(l0, 0); SA1(l0, 0); SB0(l0, 0); SB1(l0, 0);

    for (int t = 0; t < NT; ++t) {
        const __bf16* rc = (t & 1) ? &lds[1][0] : &lds[0][0];
        __bf16* sd = (t & 1) ? l0 : l1;   // stage dest: buffer (t+1)&1
        const int kn1 = (t + 1) << 6;

        VMCNT(0);      // drain stage(t) (only our own loads outstanding)
        BARM();        // all waves done reading buf[(t+1)&1] (their t-1 reads retired)

        if (t + 1 < NT) { SA0(sd, kn1); SA1(sd, kn1); SB0(sd, kn1); SB1(sd, kn1); }

        bf16x8 aE[4], aO[4], bv[4];
        // kk0 half
        read_b4(rc + 16384, wn, fr, c0, bv);
        read_a4<0>(rc, wm, fr, c0, aE);
        read_a4<1>(rc, wm, fr, c0, aO);
        mfma16<0>(acc, aE, bv);
        mfma16<1>(acc, aO, bv);
        // kk1 half
        read_b4(rc + 16384, wn, fr, c1, bv);
        read_a4<0>(rc, wm, fr, c1, aE);
        read_a4<1>(rc, wm, fr, c1, aO);
        mfma16<0>(acc, aE, bv);
        mfma16<1>(acc, aO, bv);
    }

    if (bcol >= 2560) {
        #pragma unroll
        for (int n = 0; n < 4; ++n) {
            const int col = bcol + wn * 64 + n * 16 + fr;
            const float bv = bias[col];
            const int vcol = col - 2560;
            const int hh = vcol / 80;
            const int dd = vcol - hh * 80;
            __bf16* vp = Vt + (size_t)(hh * 80 + dd) * 4096 + brow + wm * 128 + g * 4;
            #pragma unroll
            for (int m = 0; m < 8; ++m) {
                bf16x4 pk;
                #pragma unroll
                for (int j = 0; j < 4; ++j) pk[j] = (__bf16)(acc[m][n][j] + bv);
                *(bf16x4*)(vp + m * 16) = pk;
            }
        }
    } else {
        #pragma unroll
        for (int n = 0; n < 4; ++n) {
            const int col = bcol + wn * 64 + n * 16 + fr;
            const float bv = bias[col];
            #pragma unroll
            for (int m = 0; m < 8; ++m) {
                const int row = brow + wm * 128 + m * 16 + g * 4;
                #pragma unroll
                for (int j = 0; j < 4; ++j)
                    C[(size_t)(row + j) * N + col] = (__bf16)(acc[m][n][j] + bv);
            }
        }
    }
    #undef SA0
    #undef SA1
    #undef SB0
    #undef SB1
}

// ---------------- TLP-pipelined GEMM template (proj), BK=32, dbuf ----------------
template<int BM, int BN, int WM, int WN, int OUTF32>
__global__ __launch_bounds__(WM * WN * 64, 4)
void k_gemm_t(const __bf16* __restrict__ A,
              const __bf16* __restrict__ B,
              const float* __restrict__ bias,
              void* __restrict__ Cp,
              int M, int N, int K) {
    constexpr int T   = WM * WN * 64;
    constexpr int WTM = BM / WM, WTN = BN / WN;
    constexpr int AM  = WTM / 16, AN = WTN / 16;
    constexpr int LR  = BM + BN;
    constexpr int BUFE = LR * 32;
    constexpr int LP  = (LR * 4) / T;
    static_assert((LR * 4) % T == 0 && (LP == 3 || LP == 4), "stage loads per thread");

    __shared__ __align__(16) __bf16 lds[2 * BUFE];
    const int tid = threadIdx.x;
    const int lane = tid & 63, w = tid >> 6;
    const int wm = w / WN, wn = w % WN;
    const int g = lane >> 4, fr = lane & 15;

    const int nbn = N / BN;
    const int nwg = gridDim.x;
    int bid = blockIdx.x;
    {
        int q = nwg >> 3, r = nwg & 7;
        int xcd = bid & 7, o = bid >> 3;
        bid = (xcd < r ? xcd * (q + 1) : r * (q + 1) + (xcd - r) * q) + o;
    }
    const int bm = bid / nbn, bn = bid % nbn;
    const int brow = bm * BM, bcol = bn * BN;

    const __bf16* gp[LP];
    #pragma unroll
    for (int p = 0; p < LP; ++p) {
        const int sp = (tid >> 2) + p * (T / 4);
        const int cg = ((tid & 3) ^ ((sp >> 1) & 3)) << 3;
        gp[p] = (sp < BM) ? (A + (size_t)(brow + sp) * K + cg)
                          : (B + (size_t)(bcol + (sp - BM)) * K + cg);
    }
    const int NT = K >> 5;

    #define STAGE(bufsel, kt)                                                   \
        {                                                                       \
            _Pragma("unroll")                                                   \
            for (int p = 0; p < LP; ++p)                                        \
                gload16(&lds[(bufsel) * BUFE + (p * T + tid) * 8], gp[p] + (kt) * 32); \
        }

    f32x4 acc[AM][AN] = {};

    STAGE(0, 0);
    STAGE(1, 1);
    if constexpr (LP == 3) { VMCNT(3); } else { VMCNT(4); }
    BAR();

    for (int t = 0; t < NT; ++t) {
        const __bf16* buf = &lds[(t & 1) * BUFE];
        bf16x8 a[AM], b[AN];
        #pragma unroll
        for (int m = 0; m < AM; ++m) {
            const int row = wm * WTM + m * 16 + fr;
            a[m] = *(const bf16x8*)__builtin_assume_aligned(
                &buf[row * 32 + ((g ^ ((row >> 1) & 3)) << 3)], 16);
        }
        #pragma unroll
        for (int n = 0; n < AN; ++n) {
            const int row = BM + wn * WTN + n * 16 + fr;
            b[n] = *(const bf16x8*)__builtin_assume_aligned(
                &buf[row * 32 + ((g ^ ((row >> 1) & 3)) << 3)], 16);
        }
        BAR();
        __builtin_amdgcn_s_setprio(1);
        #pragma unroll
        for (int m = 0; m < AM; ++m)
            #pragma unroll
            for (int n = 0; n < AN; ++n)
                acc[m][n] = __builtin_amdgcn_mfma_f32_16x16x32_bf16(a[m], b[n], acc[m][n], 0, 0, 0);
        __builtin_amdgcn_s_setprio(0);
        if (t + 2 < NT) { STAGE(t & 1, t + 2); if constexpr (LP == 3) { VMCNT(3); } else { VMCNT(4); } }
        else            { VMCNT(0); }
        BAR();
    }
    #undef STAGE

    #pragma unroll
    for (int n = 0; n < AN; ++n) {
        const int col = bcol + wn * WTN + n * 16 + fr;
        const float bv = bias[col];
        #pragma unroll
        for (int m = 0; m < AM; ++m) {
            const int row = brow + wm * WTM + m * 16 + g * 4;
            #pragma unroll
            for (int j = 0; j < 4; ++j) {
                float v = acc[m][n][j] + bv;
                if (OUTF32) ((float*)Cp)[(size_t)(row + j) * N + col] = v;
                else        ((__bf16*)Cp)[(size_t)(row + j) * N + col] = (__bf16)v;
            }
        }
    }
}

// ---------------- K RoPE prepass: qkvb K-cols -> Kp[h][s][96] (cols 80..95 zero) ----------------
__global__ __launch_bounds__(256) void k_rope_k(const __bf16* __restrict__ qkv,
                                                const __bf16* __restrict__ csb,
                                                const __bf16* __restrict__ snb,
                                                __bf16* __restrict__ Kp) {
    const int h = blockIdx.x >> 6;
    const int s0 = (blockIdx.x & 63) * 64;
    const int tid = threadIdx.x;

    auto rope8 = [&](int srow, int c8) -> bf16x8 {
        bf16x8 v;
        if (c8 < 80) {
            const int lo = (c8 < 40) ? 1 : 0;
            const int d0 = lo ? c8 : c8 - 40;
            const __bf16* kr = qkv + (size_t)srow * 3840 + 1280 + h * 80;
            bf16x8 x = *(const bf16x8*)(kr + c8);
            bf16x8 y = *(const bf16x8*)(kr + (lo ? c8 + 40 : c8 - 40));
            bf16x8 cv = *(const bf16x8*)(csb + srow * 40 + d0);
            bf16x8 sv = *(const bf16x8*)(snb + srow * 40 + d0);
            #pragma unroll
            for (int j = 0; j < 8; ++j) {
                float xf = (float)x[j], yf = (float)y[j];
                float cf = (float)cv[j], sf = (float)sv[j];
                v[j] = (__bf16)(lo ? (xf * cf - yf * sf) : (xf * cf + yf * sf));
            }
        } else {
            #pragma unroll
            for (int j = 0; j < 8; ++j) v[j] = (__bf16)0.f;
        }
        return v;
    };

    #pragma unroll
    for (int it = 0; it < 2; ++it) {
        int slot = tid + it * 256;
        int r = slot >> 3, c8 = (slot & 7) << 3;
        bf16x8 v = rope8(s0 + r, c8);
        *(bf16x8*)(Kp + ((size_t)h * 4096 + s0 + r) * 96 + c8) = v;
    }
    {
        int r = tid >> 2, c8 = 64 + ((tid & 3) << 3);
        bf16x8 v = rope8(s0 + r, c8);
        *(bf16x8*)(Kp + ((size_t)h * 4096 + s0 + r) * 96 + c8) = v;
    }
}

// ---------------- flash attention: QBLK=256, dbuf + async reg-stage, in-register L ----------------
__global__ __launch_bounds__(512, 2) void k_attn(const __bf16* __restrict__ qkv,
                                                 const __bf16* __restrict__ csb,
                                                 const __bf16* __restrict__ snb,
                                                 const __bf16* __restrict__ Kp,
                                                 const __bf16* __restrict__ Vt,
                                                 __bf16* __restrict__ Ao) {
    __shared__ __align__(16) __bf16 Ks[2][3 * 2048];
    __shared__ __align__(16) __bf16 Vs[2][96 * 64];
    __shared__ __align__(16) __bf16 Pl[8 * 1024];

    const int blk = blockIdx.x;
    const int seg = blk & 7;
    const int qt = (blk >> 3) & 1;
    const int h = blk >> 4;
    const int tid = threadIdx.x;
    const int w = tid >> 6, lane = tid & 63;
    const int g = lane >> 4, fr = lane & 15;
    const int qrow0 = seg * 512 + qt * 256 + w * 32;
    const float qscale = 0.111803398875f * 1.44269504089f; // rsqrt(80) * log2(e)

    const int kr0 = tid >> 3, kc0 = (tid & 7) << 3;
    const int kr1 = tid >> 2, kc1 = 64 + ((tid & 3) << 3);
    const int vd0 = tid >> 3, vc0 = (tid & 7) << 3;
    const int vd1 = 64 + (tid >> 3);
    const __bf16* kbase = Kp + (size_t)h * 4096 * 96;
    const __bf16* vbase = Vt + (size_t)h * 80 * 4096;

    bf16x8 kA, kB, vA, vB;
    {
        const int t0 = seg * 512;
        kA = *(const bf16x8*)(kbase + (size_t)(t0 + kr0) * 96 + kc0);
        if (tid < 256) kB = *(const bf16x8*)(kbase + (size_t)(t0 + kr1) * 96 + kc1);
        vA = *(const bf16x8*)(vbase + (size_t)vd0 * 4096 + t0 + vc0);
        if (tid < 128) vB = *(const bf16x8*)(vbase + (size_t)vd1 * 4096 + t0 + vc0);
    }
    SCHEDB();

    bf16x8 aq[2][3];
    #pragma unroll
    for (int rg = 0; rg < 2; ++rg) {
        const int s = qrow0 + rg * 16 + fr;
        const __bf16* qrow = qkv + (size_t)s * 3840 + h * 80;
        const __bf16* cr = csb + s * 40;
        const __bf16* sr2 = snb + s * 40;
        #pragma unroll
        for (int ks = 0; ks < 3; ++ks) {
            const int cc0 = ks * 32 + g * 8;
            bf16x8 v;
            if (cc0 < 80) {
                const int lo = (cc0 < 40) ? 1 : 0;
                const int d0 = lo ? cc0 : cc0 - 40;
                bf16x8 x = *(const bf16x8*)(qrow + cc0);
                bf16x8 y = *(const bf16x8*)(qrow + (lo ? cc0 + 40 : cc0 - 40));
                bf16x8 cv = *(const bf16x8*)(cr + d0);
                bf16x8 sv = *(const bf16x8*)(sr2 + d0);
                #pragma unroll
                for (int j = 0; j < 8; ++j) {
                    float xf = (float)x[j], yf = (float)y[j];
                    float cf = (float)cv[j], sf = (float)sv[j];
                    float r = lo ? (xf * cf - yf * sf) : (xf * cf + yf * sf);
                    v[j] = (__bf16)(r * qscale);
                }
            } else {
                #pragma unroll
                for (int j = 0; j < 8; ++j) v[j] = (__bf16)0.f;
            }
            aq[rg][ks] = v;
        }
    }

    f32x4 o[2][5] = {};
    float Lacc[2] = {0.f, 0.f};
    __bf16* pw = &Pl[w * 1024];

    for (int tc = 0; tc < 8; ++tc) {
        const int p = tc & 1;

        VMCNT(0);
        {
            int pc = (kc0 & 31) ^ ((kr0 & 3) << 3);
            *(bf16x8*)&Ks[p][(kc0 >> 5) * 2048 + kr0 * 32 + pc] = kA;
        }
        if (tid < 256) {
            int pc = (kc1 & 31) ^ ((kr1 & 3) << 3);
            *(bf16x8*)&Ks[p][2 * 2048 + kr1 * 32 + pc] = kB;
        }
        *(bf16x8*)&Vs[p][vd0 * 64 + (vc0 ^ ((vd0 & 7) << 3))] = vA;
        if (tid < 128) *(bf16x8*)&Vs[p][vd1 * 64 + (vc0 ^ ((vd1 & 7) << 3))] = vB;
        LGKM0();
        BAR();

        if (tc + 1 < 8) {
            const int t1 = seg * 512 + (tc + 1) * 64;
            kA = *(const bf16x8*)(kbase + (size_t)(t1 + kr0) * 96 + kc0);
            if (tid < 256) kB = *(const bf16x8*)(kbase + (size_t)(t1 + kr1) * 96 + kc1);
            vA = *(const bf16x8*)(vbase + (size_t)vd0 * 4096 + t1 + vc0);
            if (tid < 128) vB = *(const bf16x8*)(vbase + (size_t)vd1 * 4096 + t1 + vc0);
            SCHEDB();
        }

        #pragma unroll
        for (int rg = 0; rg < 2; ++rg) {
            f32x4 sacc[4] = {};
            #pragma unroll
            for (int ks = 0; ks < 3; ++ks) {
                #pragma unroll
                for (int n = 0; n < 4; ++n) {
                    bf16x8 bk = *(const bf16x8*)&Ks[p][ks * 2048 + (n * 16 + fr) * 32 + ((g * 8) ^ ((fr & 3) << 3))];
                    sacc[n] = __builtin_amdgcn_mfma_f32_16x16x32_bf16(bk, aq[rg][ks], sacc[n], 0, 0, 0);
                }
            }

            // P = exp2(S); accumulate L in-register (sum over k: in-lane + xor16/32)
            float pv[4][4];
            float rs = 0.f;
            #pragma unroll
            for (int n = 0; n < 4; ++n)
                #pragma unroll
                for (int j = 0; j < 4; ++j) {
                    float e = exp2f(sacc[n][j]);
                    pv[n][j] = e;
                    rs += e;
                }
            rs += __shfl_xor(rs, 16);
            rs += __shfl_xor(rs, 32);
            Lacc[rg] += rs;

            #pragma unroll
            for (int n = 0; n < 4; ++n) {
                bf16x4 pk;
                #pragma unroll
                for (int j = 0; j < 4; ++j) pk[j] = (__bf16)pv[n][j];
                int col = (n * 16 + g * 4) ^ ((fr & 7) << 3);
                *(bf16x4*)&pw[fr * 64 + col] = pk;
            }

            #pragma unroll
            for (int ks2 = 0; ks2 < 2; ++ks2) {
                bf16x8 pa = *(const bf16x8*)&pw[fr * 64 + (((ks2 * 32) + g * 8) ^ ((fr & 7) << 3))];
                #pragma unroll
                for (int dt = 0; dt < 5; ++dt) {
                    bf16x8 bv = *(const bf16x8*)&Vs[p][(dt * 16 + fr) * 64 + (((ks2 * 32) + g * 8) ^ ((fr & 7) << 3))];
                    o[rg][dt] = __builtin_amdgcn_mfma_f32_16x16x32_bf16(pa, bv, o[rg][dt], 0, 0, 0);
                }
            }
        }
    }

    #pragma unroll
    for (int rg = 0; rg < 2; ++rg) {
        // L lives at lane fr=q; output rows are q = g*4+j -> fetch via shfl
        float invj[4];
        #pragma unroll
        for (int j = 0; j < 4; ++j)
            invj[j] = 1.0f / __shfl(Lacc[rg], g * 4 + j);
        #pragma unroll
        for (int dt = 0; dt < 5; ++dt)
            #pragma unroll
            for (int j = 0; j < 4; ++j)
                Ao[(size_t)(qrow0 + rg * 16 + g * 4 + j) * 1280 + h * 80 + dt * 16 + fr] =
                    (__bf16)(o[rg][dt][j] * invj[j]);
    }
}

extern "C" void kernel_launch(void* const* d_in, const int* in_sizes, int n_in,
                              void* d_out, int out_size, void* d_ws, size_t ws_size,
                              hipStream_t stream) {
    const float* hid   = (const float*)d_in[0];
    const float* rcos  = (const float*)d_in[3];
    const float* rsin  = (const float*)d_in[4];
    const float* Wqkv  = (const float*)d_in[5];
    const float* bqkv  = (const float*)d_in[6];
    const float* Wproj = (const float*)d_in[7];
    const float* bproj = (const float*)d_in[8];
    float* out = (float*)d_out;

    char* ws = (char*)d_ws;
    size_t off = 0;
    auto carve = [&](size_t bytes) -> char* {
        char* p = ws + off;
        off += (bytes + 255) & ~(size_t)255;
        return p;
    };
    __bf16* hb   = (__bf16*)carve((size_t)4096 * 1280 * 2); // later reused as attn output
    __bf16* WqT  = (__bf16*)carve((size_t)3840 * 1280 * 2);
    __bf16* WpT  = (__bf16*)carve((size_t)1280 * 1280 * 2);
    __bf16* qkvb = (__bf16*)carve((size_t)4096 * 3840 * 2);
    __bf16* Vt   = (__bf16*)carve((size_t)16 * 80 * 4096 * 2);
    __bf16* Kp   = (__bf16*)carve((size_t)16 * 4096 * 96 * 2);
    __bf16* csb  = (__bf16*)carve((size_t)4096 * 40 * 2);
    __bf16* snb  = (__bf16*)carve((size_t)4096 * 40 * 2);

    k_prep<<<6880, 256, 0, stream>>>(hid, hb, Wqkv, WqT, Wproj, WpT, rcos, rsin, csb, snb);
    k_gemm256<<<240, 512, 0, stream>>>(hb, WqT, bqkv, qkvb, Vt, 4096, 3840, 1280);
    k_rope_k<<<1024, 256, 0, stream>>>(qkvb, csb, snb, Kp);
    __bf16* attnb = hb;
    k_attn<<<256, 512, 0, stream>>>(qkvb, csb, snb, Kp, Vt, attnb);
    k_gemm_t<128, 128, 2, 2, 1><<<320, 256, 0, stream>>>(attnb, WpT, bproj, out, 4096, 1280, 1280);
}

// Round 13
// 108.010 us; speedup vs baseline: 1.0419x; 1.0419x over previous
//
#include <hip/hip_runtime.h>
#include <hip/hip_bf16.h>

typedef __bf16 bf16x8 __attribute__((ext_vector_type(8)));
typedef __bf16 bf16x4 __attribute__((ext_vector_type(4)));
typedef float  f32x4  __attribute__((ext_vector_type(4)));
typedef float  f4v    __attribute__((ext_vector_type(4)));

#define DEV __device__ __forceinline__

DEV void gload16(void* lds, const void* g) {
    __builtin_amdgcn_global_load_lds((const __attribute__((address_space(1))) void*)g,
                                     (__attribute__((address_space(3))) void*)lds, 16, 0, 0);
}

#define VMCNT(n) asm volatile("s_waitcnt vmcnt(" #n ")" ::: "memory")
#define LGKM0()  asm volatile("s_waitcnt lgkmcnt(0)" ::: "memory")
#define BAR()    __builtin_amdgcn_s_barrier()
#define BARM()   asm volatile("s_barrier" ::: "memory")
#define SCHEDB() __builtin_amdgcn_sched_barrier(0)

// ---------------- fused prepass: cvt(hid) | transpose(Wqkv) | transpose(Wproj) | cs tables ----------------
__global__ __launch_bounds__(256) void k_prep(const float* __restrict__ hid, __bf16* __restrict__ hb,
                                              const float* __restrict__ Wqkv, __bf16* __restrict__ WqT,
                                              const float* __restrict__ Wproj, __bf16* __restrict__ WpT,
                                              const float* __restrict__ rcos, const float* __restrict__ rsin,
                                              __bf16* __restrict__ csb, __bf16* __restrict__ snb) {
    __shared__ float tile[64][65];
    const int b = blockIdx.x;
    const int tid = threadIdx.x;

    if (b < 5120) {
        int i = b * 256 + tid;
        f4v v = ((const f4v*)hid)[i];
        bf16x4 o;
        #pragma unroll
        for (int j = 0; j < 4; ++j) o[j] = (__bf16)v[j];
        ((bf16x4*)hb)[i] = o;
        return;
    }
    if (b < 5120 + 1200 + 400) {
        const float* in;
        __bf16* out;
        int R, C, bb, cb;
        if (b < 5120 + 1200) { in = Wqkv; out = WqT; R = 1280; C = 3840; cb = 60; bb = b - 5120; }
        else                 { in = Wproj; out = WpT; R = 1280; C = 1280; cb = 20; bb = b - 6320; }
        int br = (bb / cb) * 64, bc = (bb % cb) * 64;
        int tx = tid & 63, ty = tid >> 6;
        #pragma unroll
        for (int i = 0; i < 16; ++i) {
            int r = i * 4 + ty;
            tile[r][tx] = in[(size_t)(br + r) * C + (bc + tx)];
        }
        __syncthreads();
        #pragma unroll
        for (int i = 0; i < 16; ++i) {
            int r = i * 4 + ty;
            out[(size_t)(bc + r) * R + (br + tx)] = (__bf16)tile[tx][r];
        }
        return;
    }
    {
        int i = (b - 6720) * 256 + tid;
        f4v cv = ((const f4v*)rcos)[i];
        f4v sv = ((const f4v*)rsin)[i];
        bf16x4 co, so;
        #pragma unroll
        for (int j = 0; j < 4; ++j) { co[j] = (__bf16)cv[j]; so[j] = (__bf16)sv[j]; }
        ((bf16x4*)csb)[i] = co;
        ((bf16x4*)snb)[i] = so;
    }
}

// ---------------- 256x256 GEMM: 1 barrier + 1 vmcnt per K-tile (R11-proven) ----------------
// LDS per buffer (elems): A quarters [4][64][64] at 0 (q0=rows0-63,q1=128-191,q2=64-127,q3=192-255)
//                         B rows [256][64] at 16384
// Swizzle (elem space): col ^= (row&7)<<3  (both stage-source and ds_read)
template<int MH>
DEV void read_a4(const __bf16* Abuf, int wm, int fr, int colsw, bf16x8 (&a)[4]) {
    const __bf16* p = Abuf + (MH * 2 + wm) * 4096 + fr * 64 + colsw;
    #pragma unroll
    for (int m = 0; m < 4; ++m)
        a[m] = *(const bf16x8*)__builtin_assume_aligned(p + m * 1024, 16);
}

DEV void read_b4(const __bf16* Bbuf, int wn, int fr, int colsw, bf16x8 (&b)[4]) {
    const __bf16* p = Bbuf + wn * 4096 + fr * 64 + colsw;
    #pragma unroll
    for (int n = 0; n < 4; ++n)
        b[n] = *(const bf16x8*)__builtin_assume_aligned(p + n * 1024, 16);
}

template<int MH>
DEV void mfma16(f32x4 (&acc)[8][4], const bf16x8 (&a)[4], const bf16x8 (&b)[4]) {
    __builtin_amdgcn_s_setprio(1);
    #pragma unroll
    for (int m = 0; m < 4; ++m)
        #pragma unroll
        for (int n = 0; n < 4; ++n)
            acc[MH * 4 + m][n] = __builtin_amdgcn_mfma_f32_16x16x32_bf16(a[m], b[n], acc[MH * 4 + m][n], 0, 0, 0);
    __builtin_amdgcn_s_setprio(0);
}

__global__ __launch_bounds__(512, 2) void k_gemm256(const __bf16* __restrict__ A,
                                                    const __bf16* __restrict__ B,
                                                    const float* __restrict__ bias,
                                                    __bf16* __restrict__ C,
                                                    __bf16* __restrict__ Vt,
                                                    int M, int N, int K) {
    __shared__ __align__(16) __bf16 lds[2][32768];
    const int tid = threadIdx.x;
    const int lane = tid & 63, w = tid >> 6;
    const int wm = w >> 2, wn = w & 3;
    const int g = lane >> 4, fr = lane & 15;

    const int nbn = N >> 8;
    const int nwg = gridDim.x;
    int bid = blockIdx.x;
    {   // bijective XCD swizzle
        int q = nwg >> 3, r = nwg & 7;
        int xcd = bid & 7, o = bid >> 3;
        bid = (xcd < r ? xcd * (q + 1) : r * (q + 1) + (xcd - r) * q) + o;
    }
    const int bm = bid / nbn, bn = bid % nbn;
    const int brow = bm << 8, bcol = bn << 8;

    const int si = tid >> 3;
    const int sc = ((tid & 7) ^ (si & 7)) << 3;
    const __bf16* Ab0 = A + (size_t)(brow + si) * K + sc;
    const __bf16* Bb0 = B + (size_t)(bcol + si) * K + sc;
    __bf16* l0 = &lds[0][0] + tid * 8;
    __bf16* l1 = &lds[1][0] + tid * 8;
    const size_t K64 = (size_t)64 * K, K128 = (size_t)128 * K, K192 = (size_t)192 * K;

    #define SA0(Lb, kt) { gload16((Lb),         Ab0 + (kt));        gload16((Lb) + 4096,  Ab0 + K128 + (kt)); }
    #define SA1(Lb, kt) { gload16((Lb) + 8192,  Ab0 + K64 + (kt));  gload16((Lb) + 12288, Ab0 + K192 + (kt)); }
    #define SB0(Lb, kt) { gload16((Lb) + 16384, Bb0 + (kt));        gload16((Lb) + 20480, Bb0 + K64 + (kt)); }
    #define SB1(Lb, kt) { gload16((Lb) + 24576, Bb0 + K128 + (kt)); gload16((Lb) + 28672, Bb0 + K192 + (kt)); }

    const int NT = K >> 6;
    f32x4 acc[8][4] = {};
    const int c0 = (g * 8) ^ ((fr & 7) << 3);
    const int c1 = c0 ^ 32;

    // prologue: stage tile0 -> buf0
    SA0(l0, 0); SA1(l0, 0); SB0(l0, 0); SB1(l0, 0);

    for (int t = 0; t < NT; ++t) {
        const __bf16* rc = (t & 1) ? &lds[1][0] : &lds[0][0];
        __bf16* sd = (t & 1) ? l0 : l1;   // stage dest: buffer (t+1)&1
        const int kn1 = (t + 1) << 6;

        VMCNT(0);      // drain stage(t) (only our own loads outstanding)
        BARM();        // all waves done reading buf[(t+1)&1] (their t-1 reads retired)

        if (t + 1 < NT) { SA0(sd, kn1); SA1(sd, kn1); SB0(sd, kn1); SB1(sd, kn1); }

        bf16x8 aE[4], aO[4], bv[4];
        // kk0 half
        read_b4(rc + 16384, wn, fr, c0, bv);
        read_a4<0>(rc, wm, fr, c0, aE);
        read_a4<1>(rc, wm, fr, c0, aO);
        mfma16<0>(acc, aE, bv);
        mfma16<1>(acc, aO, bv);
        // kk1 half
        read_b4(rc + 16384, wn, fr, c1, bv);
        read_a4<0>(rc, wm, fr, c1, aE);
        read_a4<1>(rc, wm, fr, c1, aO);
        mfma16<0>(acc, aE, bv);
        mfma16<1>(acc, aO, bv);
    }

    if (bcol >= 2560) {
        #pragma unroll
        for (int n = 0; n < 4; ++n) {
            const int col = bcol + wn * 64 + n * 16 + fr;
            const float bv = bias[col];
            const int vcol = col - 2560;
            const int hh = vcol / 80;
            const int dd = vcol - hh * 80;
            __bf16* vp = Vt + (size_t)(hh * 80 + dd) * 4096 + brow + wm * 128 + g * 4;
            #pragma unroll
            for (int m = 0; m < 8; ++m) {
                bf16x4 pk;
                #pragma unroll
                for (int j = 0; j < 4; ++j) pk[j] = (__bf16)(acc[m][n][j] + bv);
                *(bf16x4*)(vp + m * 16) = pk;
            }
        }
    } else {
        #pragma unroll
        for (int n = 0; n < 4; ++n) {
            const int col = bcol + wn * 64 + n * 16 + fr;
            const float bv = bias[col];
            #pragma unroll
            for (int m = 0; m < 8; ++m) {
                const int row = brow + wm * 128 + m * 16 + g * 4;
                #pragma unroll
                for (int j = 0; j < 4; ++j)
                    C[(size_t)(row + j) * N + col] = (__bf16)(acc[m][n][j] + bv);
            }
        }
    }
    #undef SA0
    #undef SA1
    #undef SB0
    #undef SB1
}

// ---------------- TLP-pipelined GEMM template (proj), BK=32, dbuf ----------------
template<int BM, int BN, int WM, int WN, int OUTF32>
__global__ __launch_bounds__(WM * WN * 64, 4)
void k_gemm_t(const __bf16* __restrict__ A,
              const __bf16* __restrict__ B,
              const float* __restrict__ bias,
              void* __restrict__ Cp,
              int M, int N, int K) {
    constexpr int T   = WM * WN * 64;
    constexpr int WTM = BM / WM, WTN = BN / WN;
    constexpr int AM  = WTM / 16, AN = WTN / 16;
    constexpr int LR  = BM + BN;
    constexpr int BUFE = LR * 32;
    constexpr int LP  = (LR * 4) / T;
    static_assert((LR * 4) % T == 0 && (LP == 3 || LP == 4), "stage loads per thread");

    __shared__ __align__(16) __bf16 lds[2 * BUFE];
    const int tid = threadIdx.x;
    const int lane = tid & 63, w = tid >> 6;
    const int wm = w / WN, wn = w % WN;
    const int g = lane >> 4, fr = lane & 15;

    const int nbn = N / BN;
    const int nwg = gridDim.x;
    int bid = blockIdx.x;
    {
        int q = nwg >> 3, r = nwg & 7;
        int xcd = bid & 7, o = bid >> 3;
        bid = (xcd < r ? xcd * (q + 1) : r * (q + 1) + (xcd - r) * q) + o;
    }
    const int bm = bid / nbn, bn = bid % nbn;
    const int brow = bm * BM, bcol = bn * BN;

    const __bf16* gp[LP];
    #pragma unroll
    for (int p = 0; p < LP; ++p) {
        const int sp = (tid >> 2) + p * (T / 4);
        const int cg = ((tid & 3) ^ ((sp >> 1) & 3)) << 3;
        gp[p] = (sp < BM) ? (A + (size_t)(brow + sp) * K + cg)
                          : (B + (size_t)(bcol + (sp - BM)) * K + cg);
    }
    const int NT = K >> 5;

    #define STAGE(bufsel, kt)                                                   \
        {                                                                       \
            _Pragma("unroll")                                                   \
            for (int p = 0; p < LP; ++p)                                        \
                gload16(&lds[(bufsel) * BUFE + (p * T + tid) * 8], gp[p] + (kt) * 32); \
        }

    f32x4 acc[AM][AN] = {};

    STAGE(0, 0);
    STAGE(1, 1);
    if constexpr (LP == 3) { VMCNT(3); } else { VMCNT(4); }
    BAR();

    for (int t = 0; t < NT; ++t) {
        const __bf16* buf = &lds[(t & 1) * BUFE];
        bf16x8 a[AM], b[AN];
        #pragma unroll
        for (int m = 0; m < AM; ++m) {
            const int row = wm * WTM + m * 16 + fr;
            a[m] = *(const bf16x8*)__builtin_assume_aligned(
                &buf[row * 32 + ((g ^ ((row >> 1) & 3)) << 3)], 16);
        }
        #pragma unroll
        for (int n = 0; n < AN; ++n) {
            const int row = BM + wn * WTN + n * 16 + fr;
            b[n] = *(const bf16x8*)__builtin_assume_aligned(
                &buf[row * 32 + ((g ^ ((row >> 1) & 3)) << 3)], 16);
        }
        BAR();
        __builtin_amdgcn_s_setprio(1);
        #pragma unroll
        for (int m = 0; m < AM; ++m)
            #pragma unroll
            for (int n = 0; n < AN; ++n)
                acc[m][n] = __builtin_amdgcn_mfma_f32_16x16x32_bf16(a[m], b[n], acc[m][n], 0, 0, 0);
        __builtin_amdgcn_s_setprio(0);
        if (t + 2 < NT) { STAGE(t & 1, t + 2); if constexpr (LP == 3) { VMCNT(3); } else { VMCNT(4); } }
        else            { VMCNT(0); }
        BAR();
    }
    #undef STAGE

    #pragma unroll
    for (int n = 0; n < AN; ++n) {
        const int col = bcol + wn * WTN + n * 16 + fr;
        const float bv = bias[col];
        #pragma unroll
        for (int m = 0; m < AM; ++m) {
            const int row = brow + wm * WTM + m * 16 + g * 4;
            #pragma unroll
            for (int j = 0; j < 4; ++j) {
                float v = acc[m][n][j] + bv;
                if (OUTF32) ((float*)Cp)[(size_t)(row + j) * N + col] = v;
                else        ((__bf16*)Cp)[(size_t)(row + j) * N + col] = (__bf16)v;
            }
        }
    }
}

// ---------------- flash attention: QBLK=256, dbuf + async reg-stage, FUSED K-RoPE, in-reg L ----------------
// K staging (threads 0..319): thread loads the (d, d+40) pair + cos/sin, ropes in-register,
// writes both bf16x8 swizzled. Cols 80..95 of both Ks buffers are zeroed once before the loop
// (the swizzle is a per-row bijection, staging never touches those images).
__global__ __launch_bounds__(512, 2) void k_attn(const __bf16* __restrict__ qkv,
                                                 const __bf16* __restrict__ csb,
                                                 const __bf16* __restrict__ snb,
                                                 const __bf16* __restrict__ Vt,
                                                 __bf16* __restrict__ Ao) {
    __shared__ __align__(16) __bf16 Ks[2][3 * 2048];
    __shared__ __align__(16) __bf16 Vs[2][96 * 64];
    __shared__ __align__(16) __bf16 Pl[8 * 1024];

    const int blk = blockIdx.x;
    const int seg = blk & 7;
    const int qt = (blk >> 3) & 1;
    const int h = blk >> 4;
    const int tid = threadIdx.x;
    const int w = tid >> 6, lane = tid & 63;
    const int g = lane >> 4, fr = lane & 15;
    const int qrow0 = seg * 512 + qt * 256 + w * 32;
    const float qscale = 0.111803398875f * 1.44269504089f; // rsqrt(80) * log2(e)

    // K stage geometry (fused RoPE), threads 0..319: row krow, pair base kd
    const int krow = tid / 5, ksl = tid - krow * 5;   // valid when tid < 320
    const int kd = ksl * 8;
    // V stage geometry
    const int vd0 = tid >> 3, vc0 = (tid & 7) << 3;
    const int vd1 = 64 + (tid >> 3);
    const __bf16* kqbase = qkv + 1280 + h * 80;       // + s*3840 + kd
    const __bf16* vbase = Vt + (size_t)h * 80 * 4096;

    // issue tile 0 loads into regs
    bf16x8 kx1, kx2, kcs, ksn, vA, vB;
    {
        const int s = seg * 512 + krow;
        if (tid < 320) {
            kx1 = *(const bf16x8*)(kqbase + (size_t)s * 3840 + kd);
            kx2 = *(const bf16x8*)(kqbase + (size_t)s * 3840 + kd + 40);
            kcs = *(const bf16x8*)(csb + s * 40 + kd);
            ksn = *(const bf16x8*)(snb + s * 40 + kd);
        }
        const int t0 = seg * 512;
        vA = *(const bf16x8*)(vbase + (size_t)vd0 * 4096 + t0 + vc0);
        if (tid < 128) vB = *(const bf16x8*)(vbase + (size_t)vd1 * 4096 + t0 + vc0);
    }
    SCHEDB();

    // ---- Q load + RoPE into frags (hides tile0 load latency) ----
    bf16x8 aq[2][3];
    #pragma unroll
    for (int rg = 0; rg < 2; ++rg) {
        const int s = qrow0 + rg * 16 + fr;
        const __bf16* qrow = qkv + (size_t)s * 3840 + h * 80;
        const __bf16* cr = csb + s * 40;
        const __bf16* sr2 = snb + s * 40;
        #pragma unroll
        for (int ks = 0; ks < 3; ++ks) {
            const int cc0 = ks * 32 + g * 8;
            bf16x8 v;
            if (cc0 < 80) {
                const int lo = (cc0 < 40) ? 1 : 0;
                const int d0 = lo ? cc0 : cc0 - 40;
                bf16x8 x = *(const bf16x8*)(qrow + cc0);
                bf16x8 y = *(const bf16x8*)(qrow + (lo ? cc0 + 40 : cc0 - 40));
                bf16x8 cv = *(const bf16x8*)(cr + d0);
                bf16x8 sv = *(const bf16x8*)(sr2 + d0);
                #pragma unroll
                for (int j = 0; j < 8; ++j) {
                    float xf = (float)x[j], yf = (float)y[j];
                    float cf = (float)cv[j], sf = (float)sv[j];
                    float r = lo ? (xf * cf - yf * sf) : (xf * cf + yf * sf);
                    v[j] = (__bf16)(r * qscale);
                }
            } else {
                #pragma unroll
                for (int j = 0; j < 8; ++j) v[j] = (__bf16)0.f;
            }
            aq[rg][ks] = v;
        }
    }

    // zero cols 80..95 of BOTH Ks buffers once (staging writes only cols 0..79 images)
    if (tid < 256) {
        const int buf = tid >> 7;
        const int rr = (tid >> 1) & 63;
        const int cc = 80 + ((tid & 1) << 3);
        bf16x8 z;
        #pragma unroll
        for (int j = 0; j < 8; ++j) z[j] = (__bf16)0.f;
        *(bf16x8*)&Ks[buf][2 * 2048 + rr * 32 + ((cc & 31) ^ ((rr & 3) << 3))] = z;
    }

    f32x4 o[2][5] = {};
    float Lacc[2] = {0.f, 0.f};
    __bf16* pw = &Pl[w * 1024];

    for (int tc = 0; tc < 8; ++tc) {
        const int p = tc & 1;

        // tile tc regs ready -> rope K in-register, write into LDS buffer p (swizzled)
        VMCNT(0);
        if (tid < 320) {
            bf16x8 o1, o2;
            #pragma unroll
            for (int j = 0; j < 8; ++j) {
                float x1 = (float)kx1[j], x2 = (float)kx2[j];
                float cf = (float)kcs[j], sf = (float)ksn[j];
                o1[j] = (__bf16)(x1 * cf - x2 * sf);
                o2[j] = (__bf16)(x2 * cf + x1 * sf);
            }
            const int c1 = kd, c2 = kd + 40;
            *(bf16x8*)&Ks[p][(c1 >> 5) * 2048 + krow * 32 + ((c1 & 31) ^ ((krow & 3) << 3))] = o1;
            *(bf16x8*)&Ks[p][(c2 >> 5) * 2048 + krow * 32 + ((c2 & 31) ^ ((krow & 3) << 3))] = o2;
        }
        *(bf16x8*)&Vs[p][vd0 * 64 + (vc0 ^ ((vd0 & 7) << 3))] = vA;
        if (tid < 128) *(bf16x8*)&Vs[p][vd1 * 64 + (vc0 ^ ((vd1 & 7) << 3))] = vB;
        LGKM0();
        BAR();

        // issue next tile's loads (latency hides under compute below)
        if (tc + 1 < 8) {
            const int t1 = seg * 512 + (tc + 1) * 64;
            if (tid < 320) {
                const int s = t1 + krow;
                kx1 = *(const bf16x8*)(kqbase + (size_t)s * 3840 + kd);
                kx2 = *(const bf16x8*)(kqbase + (size_t)s * 3840 + kd + 40);
                kcs = *(const bf16x8*)(csb + s * 40 + kd);
                ksn = *(const bf16x8*)(snb + s * 40 + kd);
            }
            vA = *(const bf16x8*)(vbase + (size_t)vd0 * 4096 + t1 + vc0);
            if (tid < 128) vB = *(const bf16x8*)(vbase + (size_t)vd1 * 4096 + t1 + vc0);
            SCHEDB();
        }

        #pragma unroll
        for (int rg = 0; rg < 2; ++rg) {
            f32x4 sacc[4] = {};
            #pragma unroll
            for (int ks = 0; ks < 3; ++ks) {
                #pragma unroll
                for (int n = 0; n < 4; ++n) {
                    bf16x8 bk = *(const bf16x8*)&Ks[p][ks * 2048 + (n * 16 + fr) * 32 + ((g * 8) ^ ((fr & 3) << 3))];
                    sacc[n] = __builtin_amdgcn_mfma_f32_16x16x32_bf16(bk, aq[rg][ks], sacc[n], 0, 0, 0);
                }
            }

            // P = exp2(S); accumulate L in-register (sum over k: in-lane + xor16/32)
            float pv[4][4];
            float rs = 0.f;
            #pragma unroll
            for (int n = 0; n < 4; ++n)
                #pragma unroll
                for (int j = 0; j < 4; ++j) {
                    float e = exp2f(sacc[n][j]);
                    pv[n][j] = e;
                    rs += e;
                }
            rs += __shfl_xor(rs, 16);
            rs += __shfl_xor(rs, 32);
            Lacc[rg] += rs;

            #pragma unroll
            for (int n = 0; n < 4; ++n) {
                bf16x4 pk;
                #pragma unroll
                for (int j = 0; j < 4; ++j) pk[j] = (__bf16)pv[n][j];
                int col = (n * 16 + g * 4) ^ ((fr & 7) << 3);
                *(bf16x4*)&pw[fr * 64 + col] = pk;
            }

            #pragma unroll
            for (int ks2 = 0; ks2 < 2; ++ks2) {
                bf16x8 pa = *(const bf16x8*)&pw[fr * 64 + (((ks2 * 32) + g * 8) ^ ((fr & 7) << 3))];
                #pragma unroll
                for (int dt = 0; dt < 5; ++dt) {
                    bf16x8 bv = *(const bf16x8*)&Vs[p][(dt * 16 + fr) * 64 + (((ks2 * 32) + g * 8) ^ ((fr & 7) << 3))];
                    o[rg][dt] = __builtin_amdgcn_mfma_f32_16x16x32_bf16(pa, bv, o[rg][dt], 0, 0, 0);
                }
            }
        }
    }

    #pragma unroll
    for (int rg = 0; rg < 2; ++rg) {
        float invj[4];
        #pragma unroll
        for (int j = 0; j < 4; ++j)
            invj[j] = 1.0f / __shfl(Lacc[rg], g * 4 + j);
        #pragma unroll
        for (int dt = 0; dt < 5; ++dt)
            #pragma unroll
            for (int j = 0; j < 4; ++j)
                Ao[(size_t)(qrow0 + rg * 16 + g * 4 + j) * 1280 + h * 80 + dt * 16 + fr] =
                    (__bf16)(o[rg][dt][j] * invj[j]);
    }
}

extern "C" void kernel_launch(void* const* d_in, const int* in_sizes, int n_in,
                              void* d_out, int out_size, void* d_ws, size_t ws_size,
                              hipStream_t stream) {
    const float* hid   = (const float*)d_in[0];
    const float* rcos  = (const float*)d_in[3];
    const float* rsin  = (const float*)d_in[4];
    const float* Wqkv  = (const float*)d_in[5];
    const float* bqkv  = (const float*)d_in[6];
    const float* Wproj = (const float*)d_in[7];
    const float* bproj = (const float*)d_in[8];
    float* out = (float*)d_out;

    char* ws = (char*)d_ws;
    size_t off = 0;
    auto carve = [&](size_t bytes) -> char* {
        char* p = ws + off;
        off += (bytes + 255) & ~(size_t)255;
        return p;
    };
    __bf16* hb   = (__bf16*)carve((size_t)4096 * 1280 * 2); // later reused as attn output
    __bf16* WqT  = (__bf16*)carve((size_t)3840 * 1280 * 2);
    __bf16* WpT  = (__bf16*)carve((size_t)1280 * 1280 * 2);
    __bf16* qkvb = (__bf16*)carve((size_t)4096 * 3840 * 2);
    __bf16* Vt   = (__bf16*)carve((size_t)16 * 80 * 4096 * 2);
    __bf16* csb  = (__bf16*)carve((size_t)4096 * 40 * 2);
    __bf16* snb  = (__bf16*)carve((size_t)4096 * 40 * 2);

    k_prep<<<6880, 256, 0, stream>>>(hid, hb, Wqkv, WqT, Wproj, WpT, rcos, rsin, csb, snb);
    k_gemm256<<<240, 512, 0, stream>>>(hb, WqT, bqkv, qkvb, Vt, 4096, 3840, 1280);
    __bf16* attnb = hb;
    k_attn<<<256, 512, 0, stream>>>(qkvb, csb, snb, Vt, attnb);
    k_gemm_t<128, 128, 2, 2, 1><<<320, 256, 0, stream>>>(attnb, WpT, bproj, out, 4096, 1280, 1280);
}